// Round 10
// baseline (373.586 us; speedup 1.0000x reference)
//
#include <hip/hip_runtime.h>
#include <hip/hip_fp16.h>

static constexpr int NB = 128;   // batches
static constexpr int NN = 512;   // agents (rows)
static constexpr int NM = 512;   // tasks (cols)
static constexpr int NTHREADS = 1024; // 16 waves; one wg owns one batch
static constexpr int NWAVES = 16;
static constexpr int NITER = 5;

// ROUND-10 STRUCTURE: 1 workgroup = 1 batch (128 wgs x 1024 thr). The only
// cross-row coupling (column sums) reduces intra-wg via LDS, so the whole
// 5-iteration Sinkhorn is ONE dispatch with ~12 __syncthreads and ZERO global
// syncs. Rationale: rounds 5-9 showed the 6-launch chain is dominated by
// per-dispatch fixed cost (350us vs ~70us of traffic), occupancy/wg-count
// neutral; round 7 showed grid.sync costs ~120us each. Intermediate state Y
// is fp16 in d_ws (halves traffic; values in [0,e], rel err 5e-4 << 3.3e-3
// threshold). Invalid region never stored in Y; zeros written once in FIN.
// Per wave: rows r ≡ wv (mod 16); per lane: 8 fixed cols (m0..m0+3, m1..m1+3).

__device__ __forceinline__ float wave_sum(float v) {
#pragma unroll
    for (int off = 32; off >= 1; off >>= 1) v += __shfl_xor(v, off, 64);
    return v;
}

__device__ __forceinline__ uint2 pack4(float a, float b, float c, float d) {
    __half2 lo = __floats2half2_rn(a, b), hi = __floats2half2_rn(c, d);
    uint2 r;
    r.x = *reinterpret_cast<unsigned*>(&lo);
    r.y = *reinterpret_cast<unsigned*>(&hi);
    return r;
}

__device__ __forceinline__ void unpack4(uint2 u, float* f) {
    __half2 lo = *reinterpret_cast<__half2*>(&u.x);
    __half2 hi = *reinterpret_cast<__half2*>(&u.y);
    float2 a = __half22float2(lo), b = __half22float2(hi);
    f[0] = a.x; f[1] = a.y; f[2] = b.x; f[3] = b.y;
}

__global__ __launch_bounds__(NTHREADS, 4)
void gs_all(const float* __restrict__ logits, const int* __restrict__ nfree,
            const int* __restrict__ ntask, float* __restrict__ X,
            __half* __restrict__ Y)
{
    const int b = blockIdx.x;
    const int na = nfree[b], nt = ntask[b];
    const int tid = threadIdx.x, wv = tid >> 6, lane = tid & 63;

    const float* __restrict__ Lb = logits + (size_t)b * NN * NM;
    float* __restrict__ Xb       = X + (size_t)b * NN * NM;
    __half* __restrict__ Yb      = Y + (size_t)b * NN * NM;

    __shared__ __align__(16) float red[NWAVES][NM]; // 32 KB per-wave col partials
    __shared__ __align__(16) float csh[NM];         // 2 KB col sums

    const int m0 = lane * 4, m1 = 256 + lane * 4; // this thread's 8 cols
    float msk[8];
#pragma unroll
    for (int k = 0; k < 8; ++k)
        msk[k] = (((k < 4) ? m0 + k : m1 + k - 4) < nt) ? 1.f : 0.f;

    // ---------------- P0: Y = msk*exp(rowsoftmax(exp(logits))); col partials ----------------
    float ca[8];
#pragma unroll
    for (int k = 0; k < 8; ++k) ca[k] = 0.f;

    for (int r = wv; r < na; r += NWAVES) {
        const float4 x0 = *(const float4*)(Lb + (size_t)r * NM + m0);
        const float4 x1 = *(const float4*)(Lb + (size_t)r * NM + m1);
        float e[8];
        e[0] = msk[0] * __expf(x0.x); e[1] = msk[1] * __expf(x0.y);
        e[2] = msk[2] * __expf(x0.z); e[3] = msk[3] * __expf(x0.w);
        e[4] = msk[4] * __expf(x1.x); e[5] = msk[5] * __expf(x1.y);
        e[6] = msk[6] * __expf(x1.z); e[7] = msk[7] * __expf(x1.w);
        const float sum = wave_sum(((e[0] + e[1]) + (e[2] + e[3])) +
                                   ((e[4] + e[5]) + (e[6] + e[7])));
        const float invr = (sum > 0.f) ? 1.0f / sum : 0.f;
        float o[8];
#pragma unroll
        for (int k = 0; k < 8; ++k) {
            o[k] = msk[k] * __expf(e[k] * invr);
            ca[k] += o[k];
        }
        *(uint2*)(Yb + (size_t)r * NM + m0) = pack4(o[0], o[1], o[2], o[3]);
        *(uint2*)(Yb + (size_t)r * NM + m1) = pack4(o[4], o[5], o[6], o[7]);
    }

    *(float4*)&red[wv][m0] = make_float4(ca[0], ca[1], ca[2], ca[3]);
    *(float4*)&red[wv][m1] = make_float4(ca[4], ca[5], ca[6], ca[7]);
    __syncthreads();
    if (tid < NM) {
        float s = 0.f;
#pragma unroll
        for (int w = 0; w < NWAVES; ++w) s += red[w][tid];
        csh[tid] = s;
    }
    __syncthreads();

    // ---------------- 4x fused CR: Ez=msk*exp(Y/colsum); Y'=msk*exp(Ez/rowsum) ----------------
    for (int it = 0; it < NITER - 1; ++it) {
        float inv[8];
#pragma unroll
        for (int k = 0; k < 8; ++k) {
            const int m = (k < 4) ? m0 + k : m1 + k - 4;
            inv[k] = (m < nt) ? 1.0f / csh[m] : 0.f;
        }
        float cn[8];
#pragma unroll
        for (int k = 0; k < 8; ++k) cn[k] = 0.f;

        for (int r = wv; r < na; r += NWAVES) {
            float y[8];
            unpack4(*(const uint2*)(Yb + (size_t)r * NM + m0), y);
            unpack4(*(const uint2*)(Yb + (size_t)r * NM + m1), y + 4);
            float ez[8];
#pragma unroll
            for (int k = 0; k < 8; ++k) ez[k] = msk[k] * __expf(y[k] * inv[k]);
            const float sum = wave_sum(((ez[0] + ez[1]) + (ez[2] + ez[3])) +
                                       ((ez[4] + ez[5]) + (ez[6] + ez[7])));
            const float invr = (sum > 0.f) ? 1.0f / sum : 0.f;
            float o[8];
#pragma unroll
            for (int k = 0; k < 8; ++k) {
                o[k] = msk[k] * __expf(ez[k] * invr);
                cn[k] += o[k];
            }
            *(uint2*)(Yb + (size_t)r * NM + m0) = pack4(o[0], o[1], o[2], o[3]);
            *(uint2*)(Yb + (size_t)r * NM + m1) = pack4(o[4], o[5], o[6], o[7]);
        }

        *(float4*)&red[wv][m0] = make_float4(cn[0], cn[1], cn[2], cn[3]);
        *(float4*)&red[wv][m1] = make_float4(cn[4], cn[5], cn[6], cn[7]);
        __syncthreads();
        if (tid < NM) {
            float s = 0.f;
#pragma unroll
            for (int w = 0; w < NWAVES; ++w) s += red[w][tid];
            csh[tid] = s;
        }
        __syncthreads();
    }

    // ---------------- FIN: out = Y/colsum (fp32), zeros for invalid region ----------------
    float inv[8];
#pragma unroll
    for (int k = 0; k < 8; ++k) {
        const int m = (k < 4) ? m0 + k : m1 + k - 4;
        inv[k] = (m < nt) ? 1.0f / csh[m] : 0.f;
    }
    const float4 z4 = make_float4(0.f, 0.f, 0.f, 0.f);
    for (int r = wv; r < NN; r += NWAVES) {
        if (r < na) {
            float y[8];
            unpack4(*(const uint2*)(Yb + (size_t)r * NM + m0), y);
            unpack4(*(const uint2*)(Yb + (size_t)r * NM + m1), y + 4);
            *(float4*)(Xb + (size_t)r * NM + m0) =
                make_float4(y[0] * inv[0], y[1] * inv[1], y[2] * inv[2], y[3] * inv[3]);
            *(float4*)(Xb + (size_t)r * NM + m1) =
                make_float4(y[4] * inv[4], y[5] * inv[5], y[6] * inv[6], y[7] * inv[7]);
        } else {
            *(float4*)(Xb + (size_t)r * NM + m0) = z4;
            *(float4*)(Xb + (size_t)r * NM + m1) = z4;
        }
    }
}

extern "C" void kernel_launch(void* const* d_in, const int* in_sizes, int n_in,
                              void* d_out, int out_size, void* d_ws, size_t ws_size,
                              hipStream_t stream)
{
    (void)in_sizes; (void)n_in; (void)out_size; (void)ws_size;
    const float* logits = (const float*)d_in[0];
    const int* nfree    = (const int*)d_in[1];
    const int* ntask    = (const int*)d_in[2];
    float* X  = (float*)d_out;
    __half* Y = (__half*)d_ws; // NB*NN*NM fp16 = 67 MB intermediate state

    hipLaunchKernelGGL(gs_all, dim3(NB), dim3(NTHREADS), 0, stream,
                       logits, nfree, ntask, X, Y);
}